// Round 9
// baseline (281.110 us; speedup 1.0000x reference)
//
#include <hip/hip_runtime.h>

#define L  2048
#define D  64
#define NH 16
#define NB 2
#define KT 64
#define NT 32
#define LOG2E 1.44269504088896f

using half8   = _Float16 __attribute__((ext_vector_type(8)));
using half4v  = _Float16 __attribute__((ext_vector_type(4)));
using float4v = float    __attribute__((ext_vector_type(4)));
using int4v   = int      __attribute__((ext_vector_type(4)));

#define BAR()    asm volatile("s_barrier" ::: "memory")
#define WAITV(n) asm volatile("s_waitcnt vmcnt(" #n ")" ::: "memory")
#define WAITL()  asm volatile("s_waitcnt lgkmcnt(0)" ::: "memory")

__device__ __forceinline__ void gload16(const void* g, void* l) {
    __builtin_amdgcn_global_load_lds((const __attribute__((address_space(1))) void*)g,
                                     (__attribute__((address_space(3))) void*)l, 16, 0, 0);
}
__device__ __forceinline__ void gload4(const void* g, void* l) {
    __builtin_amdgcn_global_load_lds((const __attribute__((address_space(1))) void*)g,
                                     (__attribute__((address_space(3))) void*)l, 4, 0, 0);
}

// ---------------- precompute: qh = fp16(q * log2e/8), kh = fp16(k) ----------------
__global__ __launch_bounds__(256) void prep_qk(const float* __restrict__ q,
                                               const float* __restrict__ k,
                                               _Float16* __restrict__ qh,
                                               _Float16* __restrict__ kh) {
    int i = (blockIdx.x * 256 + threadIdx.x) * 8;
    float4v a0 = *(const float4v*)(q + i);
    float4v a1 = *(const float4v*)(q + i + 4);
    float4v b0 = *(const float4v*)(k + i);
    float4v b1 = *(const float4v*)(k + i + 4);
    half8 qo, ko;
    const float s = 0.125f * LOG2E;
#pragma unroll
    for (int j = 0; j < 4; ++j) {
        qo[j]     = (_Float16)(a0[j] * s);
        qo[4 + j] = (_Float16)(a1[j] * s);
        ko[j]     = (_Float16)b0[j];
        ko[4 + j] = (_Float16)b1[j];
    }
    *(half8*)(qh + i) = qo;
    *(half8*)(kh + i) = ko;
}

// ---------------- precompute: vt[b,h,d,l] = fp16(v[b,h,l,d]) ----------------
__global__ __launch_bounds__(256) void prep_vt(const float* __restrict__ v,
                                               _Float16* __restrict__ vt) {
    __shared__ float tile[64][65];
    int bh = blockIdx.x >> 5;
    int l0 = (blockIdx.x & 31) * 64;
    const float* vb = v + (size_t)bh * L * D + (size_t)l0 * D;
    int row = threadIdx.x >> 2, c0 = (threadIdx.x & 3) * 16;
#pragma unroll
    for (int j = 0; j < 16; j += 4) {
        float4v t4 = *(const float4v*)(vb + row * D + c0 + j);
        tile[row][c0 + j + 0] = t4[0];
        tile[row][c0 + j + 1] = t4[1];
        tile[row][c0 + j + 2] = t4[2];
        tile[row][c0 + j + 3] = t4[3];
    }
    __syncthreads();
    int d = threadIdx.x >> 2, lq = (threadIdx.x & 3) * 16;
    _Float16* ob = vt + (size_t)bh * D * L + (size_t)d * L + l0 + lq;
    half8 o0, o1;
#pragma unroll
    for (int j = 0; j < 8; ++j) {
        o0[j] = (_Float16)tile[lq + j][d];
        o1[j] = (_Float16)tile[lq + 8 + j][d];
    }
    *(half8*)(ob)     = o0;
    *(half8*)(ob + 8) = o1;
}

// ------- precompute: mbh = fp16(mask ? bias*log2e : -1500) -------
__global__ __launch_bounds__(256) void prep_mbh(const int* __restrict__ mask,
                                                const float* __restrict__ bias,
                                                _Float16* __restrict__ mbh) {
    int i = (blockIdx.x * 256 + threadIdx.x) * 8;
    half8 o;
#pragma unroll
    for (int j = 0; j < 8; j += 4) {
        int4v   m = *(const int4v*)(mask + i + j);
        float4v b = *(const float4v*)(bias + i + j);
        o[j + 0] = (_Float16)(m[0] ? b[0] * LOG2E : -1500.0f);
        o[j + 1] = (_Float16)(m[1] ? b[1] * LOG2E : -1500.0f);
        o[j + 2] = (_Float16)(m[2] ? b[2] * LOG2E : -1500.0f);
        o[j + 3] = (_Float16)(m[3] ? b[3] * LOG2E : -1500.0f);
    }
    *(half8*)(mbh + i) = o;
}

// ---------------- fused attention, single QK pass ----------------
// R8 structure; R9 fixes the cross-wave LDS visibility races:
//  - lpart reduce:  ds_write -> __syncthreads() (full fence) -> read
//  - ored reduce:   ds_write -> __syncthreads() -> read
//  - t32 sweep:     lgkmcnt(0) before the in-loop barrier (raw BAR kept so
//    staged-load vmcnt pipeline is NOT drained).
__global__ __launch_bounds__(256, 4) void attn_fused(const _Float16* __restrict__ qh,
                                                     const _Float16* __restrict__ kh,
                                                     const _Float16* __restrict__ vt,
                                                     const _Float16* __restrict__ mbh,
                                                     float* __restrict__ out_ho,
                                                     float* __restrict__ out_attn) {
    __shared__ __align__(16) char arena[36864];
    __shared__ float lpart[4][16];
    _Float16* kbuf = (_Float16*)arena;             // [2][64 keys][64 d], XOR-swz
    _Float16* vbuf = (_Float16*)(arena + 16384);   // [2][64 d][64 keys], XOR-swz
    _Float16* mbuf = (_Float16*)(arena + 32768);   // [2][16 rows][64 keys], XOR-swz
    float*    t32  = (float*)(arena + 32768);      // [16][64] fp32, aliases mbuf
    float*    ored = (float*)arena;                // [64][68], aliases k/v (post-loop)

    int p  = blockIdx.x;                  // XCD x: 4 heads of one b, all q-tiles
    int l  = (p & 7) * 512 + (p >> 3);
    int b  = l >> 11, h = (l >> 7) & 15, qt = l & 127;
    int bh = b * NH + h;
    int q0 = qt * 16;

    int tid = threadIdx.x, w = tid >> 6, lane = tid & 63;
    int cg = lane & 15, grp = lane >> 4;

    const _Float16* kg = kh  + (size_t)bh * L * D;
    const _Float16* vg = vt  + (size_t)bh * D * L;
    const _Float16* mg = mbh + ((size_t)b * L + q0) * L;
    const _Float16* qg = qh  + ((size_t)bh * L + q0) * D;

    half8 aq0 = *(const half8*)(qg + cg * D + grp * 8);
    half8 aq1 = *(const half8*)(qg + cg * D + 32 + grp * 8);

    // staging lane offsets (pre-swizzled sources, linear LDS dests)
    const int krow_l = lane >> 3;                               // 0..7
    const int kchunk = ((lane & 7) ^ krow_l) * 8;               // halfs
    const int mc  = (lane & 31) >> 2;                           // m chunk 0..7
    const int mr0 = 4 * w + (lane >> 5), mr1 = mr0 + 2;         // m rows (j=0/1)
    const int msk0 = ((mc ^ (mr0 & 7)) << 3) + (lane & 3) * 2;  // src key
    const int msk1 = ((mc ^ (mr1 & 7)) << 3) + (lane & 3) * 2;

    auto stageKM = [&](int t, int bs) {
        _Float16* kd = kbuf + bs * 4096 + w * 1024;
        gload16(kg + (size_t)(t * KT + 16 * w +     krow_l) * D + kchunk, kd);
        gload16(kg + (size_t)(t * KT + 16 * w + 8 + krow_l) * D + kchunk, kd + 512);
        char* md = (char*)mbuf + bs * 2048 + w * 512;
        gload4(mg + (size_t)mr0 * L + t * KT + msk0, md);
        gload4(mg + (size_t)mr1 * L + t * KT + msk1, md + 256);
    };
    auto stageV = [&](int t, int bs) {
        _Float16* vd = vbuf + bs * 4096 + w * 1024;
        gload16(vg + (size_t)(16 * w +     krow_l) * L + t * KT + kchunk, vd);
        gload16(vg + (size_t)(16 * w + 8 + krow_l) * L + t * KT + kchunk, vd + 512);
    };

    // ---------------- QK loop: e -> registers ----------------
    half4v puh[NT];
    float ls = 0.f;
    const int kro = (16 * w + cg) * 64;              // kbuf row offset (halfs)
    const int ks0 = (grp ^ (cg & 7)) * 8;
    const int ks1 = ((4 + grp) ^ (cg & 7)) * 8;
    const int mro = cg * 64 + (((2 * w + (grp >> 1)) ^ (cg & 7)) * 8) + (grp & 1) * 4;

    stageKM(0, 0);
#pragma unroll
    for (int t = 0; t < NT; ++t) {
        const int bs = t & 1;
        if (t + 1 < NT) { stageKM(t + 1, bs ^ 1); WAITV(4); }
        else            { WAITV(0); }
        BAR();
        const _Float16* kb = kbuf + bs * 4096;
        const _Float16* mb = mbuf + bs * 1024;
        half8 bk0 = *(const half8*)(kb + kro + ks0);
        half8 bk1 = *(const half8*)(kb + kro + ks1);
        half4v m4 = *(const half4v*)(mb + mro);
        float4v acc;
        acc[0] = (float)m4[0]; acc[1] = (float)m4[1];
        acc[2] = (float)m4[2]; acc[3] = (float)m4[3];
        __builtin_amdgcn_s_setprio(1);
        acc = __builtin_amdgcn_mfma_f32_16x16x32_f16(bk0, aq0, acc, 0, 0, 0);
        acc = __builtin_amdgcn_mfma_f32_16x16x32_f16(bk1, aq1, acc, 0, 0, 0);
        __builtin_amdgcn_s_setprio(0);
        float e0 = exp2f(acc[0]), e1 = exp2f(acc[1]);
        float e2 = exp2f(acc[2]), e3 = exp2f(acc[3]);
        ls += (e0 + e1) + (e2 + e3);
        half4v ph;
        ph[0] = (_Float16)(e0 * 0.03125f); ph[1] = (_Float16)(e1 * 0.03125f);
        ph[2] = (_Float16)(e2 * 0.03125f); ph[3] = (_Float16)(e3 * 0.03125f);
        puh[t] = ph;
        BAR();
    }

    // l reduce: in-wave over grp, then cross-wave via lpart.
    // __syncthreads(): full fence so every wave's lpart write is VISIBLE
    // (raw s_barrier does not drain ds_write -> R8's absmax-310 race).
    ls += __shfl_xor(ls, 16);
    ls += __shfl_xor(ls, 32);
    if (grp == 0) lpart[w][cg] = ls;
    __syncthreads();
    float lt = (lpart[0][cg] + lpart[1][cg]) + (lpart[2][cg] + lpart[3][cg]);
    _Float16 rl_h = (_Float16)(32.0f / lt);          // folds the 2^-5 scale

    // ---------------- PV loop + attn stores ----------------
    float* arow = out_attn + ((size_t)bh * L + q0) * L;
    float4v oa0 = {0.f,0.f,0.f,0.f}, oa1 = {0.f,0.f,0.f,0.f};
    float4v oa2 = {0.f,0.f,0.f,0.f}, oa3 = {0.f,0.f,0.f,0.f};
    const int g32   = 4 * w + grp;                   // t32 write granule
    const int t32wo = cg * 64 + ((g32 ^ (cg & 7)) * 4);
    const int vsw   = ((2 * w + (grp >> 1)) ^ (cg & 7)) * 8 + (grp & 1) * 4;
    const int swrow = tid >> 4, swg = tid & 15;      // store-sweep coords
    const int t32ro = swrow * 64 + ((swg ^ (swrow & 7)) * 4);

    stageV(0, 0);
#pragma unroll
    for (int t = 0; t < NT; ++t) {
        const int bs = t & 1;
        if (t + 1 < NT) { stageV(t + 1, bs ^ 1); if (t == 0) { WAITV(2); } else { WAITV(3); } }
        else            { WAITV(1); }
        BAR();
        half4v pa;
        pa[0] = puh[t][0] * rl_h; pa[1] = puh[t][1] * rl_h;
        pa[2] = puh[t][2] * rl_h; pa[3] = puh[t][3] * rl_h;
        float4v pn;
        pn[0] = (float)pa[0]; pn[1] = (float)pa[1];
        pn[2] = (float)pa[2]; pn[3] = (float)pa[3];
        *(float4v*)(t32 + t32wo) = pn;
        const _Float16* vb = vbuf + bs * 4096;
        half4v pv0 = *(const half4v*)(vb + ( 0 + cg) * 64 + vsw);
        half4v pv1 = *(const half4v*)(vb + (16 + cg) * 64 + vsw);
        half4v pv2 = *(const half4v*)(vb + (32 + cg) * 64 + vsw);
        half4v pv3 = *(const half4v*)(vb + (48 + cg) * 64 + vsw);
        __builtin_amdgcn_s_setprio(1);
        oa0 = __builtin_amdgcn_mfma_f32_16x16x16f16(pa, pv0, oa0, 0, 0, 0);
        oa1 = __builtin_amdgcn_mfma_f32_16x16x16f16(pa, pv1, oa1, 0, 0, 0);
        oa2 = __builtin_amdgcn_mfma_f32_16x16x16f16(pa, pv2, oa2, 0, 0, 0);
        oa3 = __builtin_amdgcn_mfma_f32_16x16x16f16(pa, pv3, oa3, 0, 0, 0);
        __builtin_amdgcn_s_setprio(0);
        WAITL();                     // drain t32 ds_write before cross-wave read
        BAR();
        float4v s = *(const float4v*)(t32 + t32ro);
        __builtin_nontemporal_store(s, (float4v*)(arow + (size_t)swrow * L + t * KT + swg * 4));
    }

    // ---------------- cross-wave O reduction (ored aliases kbuf/vbuf) ----------------
#pragma unroll
    for (int r = 0; r < 4; ++r) {
        ored[(w * 16 + grp * 4 + r) * 68 +  0 + cg] = oa0[r];
        ored[(w * 16 + grp * 4 + r) * 68 + 16 + cg] = oa1[r];
        ored[(w * 16 + grp * 4 + r) * 68 + 32 + cg] = oa2[r];
        ored[(w * 16 + grp * 4 + r) * 68 + 48 + cg] = oa3[r];
    }
    __syncthreads();                 // full fence (raw BAR raced in R8)
    int qr = tid >> 4, d4 = (tid & 15) * 4;
    float4v o0 = *(const float4v*)(ored + ( 0 + qr) * 68 + d4);
    float4v o1 = *(const float4v*)(ored + (16 + qr) * 68 + d4);
    float4v o2 = *(const float4v*)(ored + (32 + qr) * 68 + d4);
    float4v o3 = *(const float4v*)(ored + (48 + qr) * 68 + d4);
    float4v oo;
    oo[0] = (o0[0] + o1[0]) + (o2[0] + o3[0]);
    oo[1] = (o0[1] + o1[1]) + (o2[1] + o3[1]);
    oo[2] = (o0[2] + o1[2]) + (o2[2] + o3[2]);
    oo[3] = (o0[3] + o1[3]) + (o2[3] + o3[3]);
    __builtin_nontemporal_store(oo, (float4v*)(out_ho + ((size_t)bh * L + q0 + qr) * D + d4));
}

extern "C" void kernel_launch(void* const* d_in, const int* in_sizes, int n_in,
                              void* d_out, int out_size, void* d_ws, size_t ws_size,
                              hipStream_t stream) {
    const float* q    = (const float*)d_in[0];
    const float* k    = (const float*)d_in[1];
    const float* v    = (const float*)d_in[2];
    const int*   mask = (const int*)d_in[3];
    const float* bias = (const float*)d_in[4];

    float* ho   = (float*)d_out;
    float* attn = (float*)d_out + (size_t)NB * NH * L * D;

    char* ws = (char*)d_ws;
    _Float16* qh  = (_Float16*)(ws);                       // 8 MB
    _Float16* kh  = (_Float16*)(ws + ((size_t)8  << 20));  // 8 MB
    _Float16* vt  = (_Float16*)(ws + ((size_t)16 << 20));  // 8 MB
    _Float16* mbh = (_Float16*)(ws + ((size_t)24 << 20));  // 16.8 MB
    (void)in_sizes; (void)n_in; (void)out_size; (void)ws_size;

    prep_qk<<<2048, 256, 0, stream>>>(q, k, qh, kh);
    prep_vt<<<1024, 256, 0, stream>>>(v, vt);
    prep_mbh<<<4096, 256, 0, stream>>>(mask, bias, mbh);
    attn_fused<<<4096, 256, 0, stream>>>(qh, kh, vt, mbh, ho, attn);
}

// Round 10
// 245.629 us; speedup vs baseline: 1.1444x; 1.1444x over previous
//
#include <hip/hip_runtime.h>

#define L  2048
#define D  64
#define NH 16
#define NB 2
#define KT 64
#define NT 32
#define LOG2E 1.44269504088896f

using half8   = _Float16 __attribute__((ext_vector_type(8)));
using half4v  = _Float16 __attribute__((ext_vector_type(4)));
using float4v = float    __attribute__((ext_vector_type(4)));
using int4v   = int      __attribute__((ext_vector_type(4)));

#define BAR()    asm volatile("s_barrier" ::: "memory")
#define WAITV(n) asm volatile("s_waitcnt vmcnt(" #n ")" ::: "memory")
#define WAITL()  asm volatile("s_waitcnt lgkmcnt(0)" ::: "memory")

__device__ __forceinline__ void gload16(const void* g, void* l) {
    __builtin_amdgcn_global_load_lds((const __attribute__((address_space(1))) void*)g,
                                     (__attribute__((address_space(3))) void*)l, 16, 0, 0);
}
__device__ __forceinline__ void gload4(const void* g, void* l) {
    __builtin_amdgcn_global_load_lds((const __attribute__((address_space(1))) void*)g,
                                     (__attribute__((address_space(3))) void*)l, 4, 0, 0);
}

// ---------------- precompute: qh = fp16(q * log2e/8), kh = fp16(k) ----------------
__global__ __launch_bounds__(256) void prep_qk(const float* __restrict__ q,
                                               const float* __restrict__ k,
                                               _Float16* __restrict__ qh,
                                               _Float16* __restrict__ kh) {
    int i = (blockIdx.x * 256 + threadIdx.x) * 8;
    float4v a0 = *(const float4v*)(q + i);
    float4v a1 = *(const float4v*)(q + i + 4);
    float4v b0 = *(const float4v*)(k + i);
    float4v b1 = *(const float4v*)(k + i + 4);
    half8 qo, ko;
    const float s = 0.125f * LOG2E;
#pragma unroll
    for (int j = 0; j < 4; ++j) {
        qo[j]     = (_Float16)(a0[j] * s);
        qo[4 + j] = (_Float16)(a1[j] * s);
        ko[j]     = (_Float16)b0[j];
        ko[4 + j] = (_Float16)b1[j];
    }
    *(half8*)(qh + i) = qo;
    *(half8*)(kh + i) = ko;
}

// ---------------- precompute: vt[b,h,d,l] = fp16(v[b,h,l,d]) ----------------
__global__ __launch_bounds__(256) void prep_vt(const float* __restrict__ v,
                                               _Float16* __restrict__ vt) {
    __shared__ float tile[64][65];
    int bh = blockIdx.x >> 5;
    int l0 = (blockIdx.x & 31) * 64;
    const float* vb = v + (size_t)bh * L * D + (size_t)l0 * D;
    int row = threadIdx.x >> 2, c0 = (threadIdx.x & 3) * 16;
#pragma unroll
    for (int j = 0; j < 16; j += 4) {
        float4v t4 = *(const float4v*)(vb + row * D + c0 + j);
        tile[row][c0 + j + 0] = t4[0];
        tile[row][c0 + j + 1] = t4[1];
        tile[row][c0 + j + 2] = t4[2];
        tile[row][c0 + j + 3] = t4[3];
    }
    __syncthreads();
    int d = threadIdx.x >> 2, lq = (threadIdx.x & 3) * 16;
    _Float16* ob = vt + (size_t)bh * D * L + (size_t)d * L + l0 + lq;
    half8 o0, o1;
#pragma unroll
    for (int j = 0; j < 8; ++j) {
        o0[j] = (_Float16)tile[lq + j][d];
        o1[j] = (_Float16)tile[lq + 8 + j][d];
    }
    *(half8*)(ob)     = o0;
    *(half8*)(ob + 8) = o1;
}

// ------- precompute: mbh = fp16(mask ? bias*log2e : -1500) -------
__global__ __launch_bounds__(256) void prep_mbh(const int* __restrict__ mask,
                                                const float* __restrict__ bias,
                                                _Float16* __restrict__ mbh) {
    int i = (blockIdx.x * 256 + threadIdx.x) * 8;
    half8 o;
#pragma unroll
    for (int j = 0; j < 8; j += 4) {
        int4v   m = *(const int4v*)(mask + i + j);
        float4v b = *(const float4v*)(bias + i + j);
        o[j + 0] = (_Float16)(m[0] ? b[0] * LOG2E : -1500.0f);
        o[j + 1] = (_Float16)(m[1] ? b[1] * LOG2E : -1500.0f);
        o[j + 2] = (_Float16)(m[2] ? b[2] * LOG2E : -1500.0f);
        o[j + 3] = (_Float16)(m[3] ? b[3] * LOG2E : -1500.0f);
    }
    *(half8*)(mbh + i) = o;
}

// ---------------- fused attention: barrier-free main loop ----------------
// block = 16 q-rows, 4 waves; wave w owns keys {t*64 + 16w .. +16} of every
// 64-key tile. ALL staging buffers are WAVE-PRIVATE (wave stages and reads
// only its own keys) -> main loop has ZERO barriers: each wave runs its own
// vmcnt-gated double-buffered pipeline (6 loads/tile, depth 1).
// Loop 1 (merged): QK (swapped, 2xMFMA k=32) -> e=exp2 -> puh[t] fp16 regs
//   -> PV accumulate with UNNORMALIZED pa (rl folded into O at end).
// Loop 2: attn stores only -- no global reads, no vmem waits: puh*rl ->
//   t32 LDS (double-buffered, 1 barrier/iter) -> 256B-contiguous NT stores.
__global__ __launch_bounds__(256, 4) void attn_fused(const _Float16* __restrict__ qh,
                                                     const _Float16* __restrict__ kh,
                                                     const _Float16* __restrict__ vt,
                                                     const _Float16* __restrict__ mbh,
                                                     float* __restrict__ out_ho,
                                                     float* __restrict__ out_attn) {
    // arena: [0,16K) kbuf [w][bs][16 key][64 d] | [16K,32K) vbuf [w][bs][64 d][16 key]
    //        [32K,36K) mbuf [w][bs][16 row][16 key]
    // post-loop1 aliases: t32 dbuf [2][16][64] f32 at [0,8K); ored [4][16][68] f32 at [8K,25K)
    __shared__ __align__(16) char arena[36864];
    __shared__ float lpart[4][16];
    __shared__ float rls[16];

    int p  = blockIdx.x;                  // XCD x: 4 heads of one b, all q-tiles
    int l  = (p & 7) * 512 + (p >> 3);
    int b  = l >> 11, h = (l >> 7) & 15, qt = l & 127;
    int bh = b * NH + h;
    int q0 = qt * 16;

    int tid = threadIdx.x, w = tid >> 6, lane = tid & 63;
    int cg = lane & 15, grp = lane >> 4;

    const _Float16* kg = kh  + (size_t)bh * L * D;        // [l][d]
    const _Float16* vg = vt  + (size_t)bh * D * L;        // [d][l]
    const _Float16* mg = mbh + ((size_t)b * L + q0) * L;  // [row][key], rows q0..
    const _Float16* qg = qh  + ((size_t)bh * L + q0) * D;

    half8 aq0 = *(const half8*)(qg + cg * D + grp * 8);
    half8 aq1 = *(const half8*)(qg + cg * D + 32 + grp * 8);

    _Float16* kbw = (_Float16*)(arena)         + w * 2048;   // 2 bufs x 1024 halfs
    _Float16* vbw = (_Float16*)(arena + 16384) + w * 2048;
    _Float16* mbw = (_Float16*)(arena + 32768) + w * 512;    // 2 bufs x 256 halfs

    // staging lane offsets (K source d-chunk XOR-preswizzled; dests linear)
    const int r8  = lane >> 3;                    // 0..7
    const int kch = ((lane & 7) ^ r8) * 8;        // K src chunk (halfs)
    const int vrow = lane >> 1, vkh = (lane & 1) * 8;
    const int mkey = (lane & 7) * 2;

    auto stage = [&](int t, int bs) {
        int k0 = t * KT + 16 * w;                 // wave's 16 keys this tile
        _Float16* kd = kbw + bs * 1024;
        gload16(kg + (size_t)(k0 +     r8) * D + kch, kd);
        gload16(kg + (size_t)(k0 + 8 + r8) * D + kch, kd + 512);
        _Float16* vd = vbw + bs * 1024;
        gload16(vg + (size_t)(vrow)      * L + k0 + vkh, vd);
        gload16(vg + (size_t)(32 + vrow) * L + k0 + vkh, vd + 512);
        _Float16* md = mbw + bs * 256;
        gload4(mg + (size_t)(r8)     * L + k0 + mkey, md);
        gload4(mg + (size_t)(8 + r8) * L + k0 + mkey, md + 128);
    };

    const int kro = cg * 64;                      // K row (16 local keys x 64 d)
    const int ks0 = ((grp)     ^ (cg & 7)) * 8;
    const int ks1 = ((4 + grp) ^ (cg & 7)) * 8;
    const int mro = cg * 16 + grp * 4;            // M[row cg][keys grp*4..]
    const int vro = grp * 4;

    half4v puh[NT];                               // unnormalized e * 2^-5 (64 VGPRs)
    float ls = 0.f;
    float4v oa0 = {0.f,0.f,0.f,0.f}, oa1 = {0.f,0.f,0.f,0.f};
    float4v oa2 = {0.f,0.f,0.f,0.f}, oa3 = {0.f,0.f,0.f,0.f};

    // ---------------- loop 1: barrier-free QK + PV ----------------
    stage(0, 0);
#pragma unroll
    for (int t = 0; t < NT; ++t) {
        const int bs = t & 1;
        if (t + 1 < NT) { stage(t + 1, bs ^ 1); WAITV(6); }
        else            { WAITV(0); }
        const _Float16* kb = kbw + bs * 1024;
        const _Float16* mb = mbw + bs * 256;
        const _Float16* vb = vbw + bs * 1024;
        half8  bk0 = *(const half8*)(kb + kro + ks0);
        half8  bk1 = *(const half8*)(kb + kro + ks1);
        half4v m4  = *(const half4v*)(mb + mro);
        float4v acc;
        acc[0] = (float)m4[0]; acc[1] = (float)m4[1];
        acc[2] = (float)m4[2]; acc[3] = (float)m4[3];
        __builtin_amdgcn_s_setprio(1);
        acc = __builtin_amdgcn_mfma_f32_16x16x32_f16(bk0, aq0, acc, 0, 0, 0);
        acc = __builtin_amdgcn_mfma_f32_16x16x32_f16(bk1, aq1, acc, 0, 0, 0);
        __builtin_amdgcn_s_setprio(0);
        float e0 = exp2f(acc[0]), e1 = exp2f(acc[1]);
        float e2 = exp2f(acc[2]), e3 = exp2f(acc[3]);
        ls += (e0 + e1) + (e2 + e3);
        half4v ph;
        ph[0] = (_Float16)(e0 * 0.03125f); ph[1] = (_Float16)(e1 * 0.03125f);
        ph[2] = (_Float16)(e2 * 0.03125f); ph[3] = (_Float16)(e3 * 0.03125f);
        puh[t] = ph;
        half4v pv0 = *(const half4v*)(vb + (cg +  0) * 16 + vro);
        half4v pv1 = *(const half4v*)(vb + (cg + 16) * 16 + vro);
        half4v pv2 = *(const half4v*)(vb + (cg + 32) * 16 + vro);
        half4v pv3 = *(const half4v*)(vb + (cg + 48) * 16 + vro);
        __builtin_amdgcn_s_setprio(1);
        oa0 = __builtin_amdgcn_mfma_f32_16x16x16f16(ph, pv0, oa0, 0, 0, 0);
        oa1 = __builtin_amdgcn_mfma_f32_16x16x16f16(ph, pv1, oa1, 0, 0, 0);
        oa2 = __builtin_amdgcn_mfma_f32_16x16x16f16(ph, pv2, oa2, 0, 0, 0);
        oa3 = __builtin_amdgcn_mfma_f32_16x16x16f16(ph, pv3, oa3, 0, 0, 0);
        __builtin_amdgcn_s_setprio(0);
    }

    // ---------------- l reduce (cross-wave: keys are split) ----------------
    ls += __shfl_xor(ls, 16);
    ls += __shfl_xor(ls, 32);
    if (grp == 0) lpart[w][cg] = ls;
    __syncthreads();                      // full fence; also closes loop-1 LDS use
    float lt = (lpart[0][cg] + lpart[1][cg]) + (lpart[2][cg] + lpart[3][cg]);
    float rl = 32.0f / lt;                // folds the 2^-5 e-scale
    if (w == 0 && grp == 0) rls[cg] = rl;

    // ---------------- O reduce across waves + ho store ----------------
    // lane holds O_unnorm[row=grp*4+r][d=cg+16*blk] partial (its key quarter)
    float* ored = (float*)(arena + 8192);
    float* orw  = ored + w * (16 * 68);
#pragma unroll
    for (int r = 0; r < 4; ++r) {
        orw[(grp * 4 + r) * 68 +  0 + cg] = oa0[r];
        orw[(grp * 4 + r) * 68 + 16 + cg] = oa1[r];
        orw[(grp * 4 + r) * 68 + 32 + cg] = oa2[r];
        orw[(grp * 4 + r) * 68 + 48 + cg] = oa3[r];
    }
    __syncthreads();
    {
        int qr = tid >> 4, d4 = (tid & 15) * 4;
        float4v s0 = *(const float4v*)(ored + 0 * 1088 + qr * 68 + d4);
        float4v s1 = *(const float4v*)(ored + 1 * 1088 + qr * 68 + d4);
        float4v s2 = *(const float4v*)(ored + 2 * 1088 + qr * 68 + d4);
        float4v s3 = *(const float4v*)(ored + 3 * 1088 + qr * 68 + d4);
        float rlo = rls[qr];
        float4v oo;
        oo[0] = ((s0[0] + s1[0]) + (s2[0] + s3[0])) * rlo;
        oo[1] = ((s0[1] + s1[1]) + (s2[1] + s3[1])) * rlo;
        oo[2] = ((s0[2] + s1[2]) + (s2[2] + s3[2])) * rlo;
        oo[3] = ((s0[3] + s1[3]) + (s2[3] + s3[3])) * rlo;
        __builtin_nontemporal_store(oo, (float4v*)(out_ho + ((size_t)bh * L + q0 + qr) * D + d4));
    }

    // ---------------- loop 2: attn stores (no global reads, no vmem waits) ----------------
    float* arow = out_attn + ((size_t)bh * L + q0) * L;
    float* t32f = (float*)arena;                       // dbuf [2][16][64] f32
    const int c_w   = (w * 4 + grp) ^ (cg & 7);        // swizzled chunk slot
    const int t32wo = cg * 64 + c_w * 4;
    const int swrow = tid >> 4, jj = tid & 15;
    const int t32ro = swrow * 64 + ((jj ^ (swrow & 7)) * 4);

#pragma unroll
    for (int t = 0; t < NT; ++t) {
        float* tb = t32f + (t & 1) * 1024;
        float4v pn;
        pn[0] = (float)puh[t][0] * rl; pn[1] = (float)puh[t][1] * rl;
        pn[2] = (float)puh[t][2] * rl; pn[3] = (float)puh[t][3] * rl;
        *(float4v*)(tb + t32wo) = pn;
        WAITL();                                   // my ds_write visible
        BAR();                                     // all waves' writes visible
        float4v s = *(const float4v*)(tb + t32ro);
        __builtin_nontemporal_store(s, (float4v*)(arow + (size_t)swrow * L + t * KT + jj * 4));
        // next iter writes the OTHER t32 buffer; its prior readers retired
        // before their BAR above -> single barrier per iter is sufficient.
    }
}

extern "C" void kernel_launch(void* const* d_in, const int* in_sizes, int n_in,
                              void* d_out, int out_size, void* d_ws, size_t ws_size,
                              hipStream_t stream) {
    const float* q    = (const float*)d_in[0];
    const float* k    = (const float*)d_in[1];
    const float* v    = (const float*)d_in[2];
    const int*   mask = (const int*)d_in[3];
    const float* bias = (const float*)d_in[4];

    float* ho   = (float*)d_out;
    float* attn = (float*)d_out + (size_t)NB * NH * L * D;

    char* ws = (char*)d_ws;
    _Float16* qh  = (_Float16*)(ws);                       // 8 MB
    _Float16* kh  = (_Float16*)(ws + ((size_t)8  << 20));  // 8 MB
    _Float16* vt  = (_Float16*)(ws + ((size_t)16 << 20));  // 8 MB
    _Float16* mbh = (_Float16*)(ws + ((size_t)24 << 20));  // 16.8 MB
    (void)in_sizes; (void)n_in; (void)out_size; (void)ws_size;

    prep_qk<<<2048, 256, 0, stream>>>(q, k, qh, kh);
    prep_vt<<<1024, 256, 0, stream>>>(v, vt);
    prep_mbh<<<4096, 256, 0, stream>>>(mask, bias, mbh);
    attn_fused<<<4096, 256, 0, stream>>>(qh, kh, vt, mbh, ho, attn);
}